// Round 8
// baseline (282.088 us; speedup 1.0000x reference)
//
#include <hip/hip_runtime.h>

// DACGLSTMExpert: 18432 independent CGLSTM sequences, T=120, H=32, DIN=1.
// Lane l of each 32-lane group = hidden index; 2 sequences per wave64.
//
// Allocator model (rounds 1-7): default arch-VGPR cap ~84-88 (6-wave
// heuristic target) regardless of launch bounds; amdgpu_waves_per_eu(4,4)
// LOWERED it to 64; anything over the cap goes to AGPRs and every VALU use
// pays a v_accvgpr_read (~64 extra instr/step = the measured 226 vs ~95
// ideal). Fix: NO allocator attributes, and live-set trimmed under the cap:
// f16 weight pairs (64 VGPRs), per-step uniform x read (no 4-reg x batch),
// h-quads read just-in-time (<=4 transient regs).
// o-gate is dead code in the reference and skipped (validated rounds 1-7).

constexpr int T = 120;
constexpr int H = 32;
constexpr int NSEQ = 2048 * 9;        // 18432
constexpr int SEQ_PER_BLOCK = 8;      // 256 threads / 32 lanes per seq
constexpr int BLOCK = 256;

typedef _Float16 f16;
typedef _Float16 h2 __attribute__((ext_vector_type(2)));
typedef float v4f __attribute__((ext_vector_type(4)));

#define LOG2E 1.4426950408889634f

__device__ __forceinline__ float fast_rcp(float x) {
    return __builtin_amdgcn_rcpf(x);
}
__device__ __forceinline__ float fast_exp2(float x) {
    return __builtin_amdgcn_exp2f(x);
}
// sigmoid(x) = 1 / (1 + 2^(-x*log2e))   (4 VALU)
__device__ __forceinline__ float sigmoid_f(float x) {
    return fast_rcp(1.0f + fast_exp2(-LOG2E * x));
}
// tanh(x) = 1 - 2/(2^(2x*log2e) + 1)    (5 VALU)
__device__ __forceinline__ float tanh_f(float x) {
    return fmaf(-2.0f, fast_rcp(1.0f + fast_exp2(2.0f * LOG2E * x)), 1.0f);
}

// acc += dot2(hv, wv) with f32 accumulate (v_dot2_f32_f16).
#if __has_builtin(__builtin_amdgcn_fdot2)
#define DOT2(acc, hv, wv) (acc) = __builtin_amdgcn_fdot2((hv), (wv), (acc), false)
#else
#define DOT2(acc, hv, wv) asm("v_dot2_f32_f16 %0, %1, %2, %0" \
                              : "+v"(acc) : "v"(hv), "v"(wv))
#endif

// One h-pair (32-bit word) against the 4 gate weight-pairs at index idx.
#define DOTBLK(word, idx)                                \
    {                                                    \
        const h2 hv = __builtin_bit_cast(h2, (word));    \
        DOT2(aI, hv, wi2[idx]);                          \
        DOT2(aF, hv, wf2[idx]);                          \
        DOT2(aG, hv, wg2[idx]);                          \
        DOT2(aC, hv, wc2[idx]);                          \
    }

__global__ __launch_bounds__(BLOCK)
void cglstm_kernel(
    const float* __restrict__ x,      // [NSEQ, T]
    const float* __restrict__ W_ih,   // [4H, 1]
    const float* __restrict__ W_hh,   // [4H, H]
    const float* __restrict__ b_ih,   // [4H]
    const float* __restrict__ b_hh,   // [4H]
    const float* __restrict__ W_cg_x, // [H, 1]
    const float* __restrict__ W_cg_h, // [H, H]
    const float* __restrict__ b_cg,   // [H]
    float* __restrict__ out)          // [NSEQ, H]
{
    __shared__ float xs[SEQ_PER_BLOCK * T];                 // 3840 B
    __shared__ __align__(16) f16 hs[SEQ_PER_BLOCK * H];     // 512 B

    const int tid = threadIdx.x;
    const int l   = tid & 31;          // hidden index within sequence
    const int sib = tid >> 5;          // sequence-in-block 0..7
    const int seq = blockIdx.x * SEQ_PER_BLOCK + sib;

    // --- stage this block's x rows into LDS (fully coalesced) ---
    const float* xblk = x + (size_t)blockIdx.x * SEQ_PER_BLOCK * T;
    for (int i = tid; i < SEQ_PER_BLOCK * T; i += BLOCK)
        xs[i] = xblk[i];

    // --- per-lane weights as f16 pairs: 4 gates x 16 pairs = 64 VGPRs ---
    h2 wi2[H / 2], wf2[H / 2], wg2[H / 2], wc2[H / 2];
    {
        const v4f* ri = (const v4f*)(W_hh + (size_t)(0 * H + l) * H);
        const v4f* rf = (const v4f*)(W_hh + (size_t)(1 * H + l) * H);
        const v4f* rg = (const v4f*)(W_hh + (size_t)(2 * H + l) * H);
        const v4f* rc = (const v4f*)(W_cg_h + (size_t)l * H);
        #pragma unroll
        for (int q = 0; q < H / 4; ++q) {
            v4f vi = ri[q], vf = rf[q], vg = rg[q], vc = rc[q];
            wi2[2*q]   = h2{(f16)vi.x, (f16)vi.y};
            wi2[2*q+1] = h2{(f16)vi.z, (f16)vi.w};
            wf2[2*q]   = h2{(f16)vf.x, (f16)vf.y};
            wf2[2*q+1] = h2{(f16)vf.z, (f16)vf.w};
            wg2[2*q]   = h2{(f16)vg.x, (f16)vg.y};
            wg2[2*q+1] = h2{(f16)vg.z, (f16)vg.w};
            wc2[2*q]   = h2{(f16)vc.x, (f16)vc.y};
            wc2[2*q+1] = h2{(f16)vc.z, (f16)vc.w};
        }
    }
    const float wi_i = W_ih[0 * H + l];
    const float wi_f = W_ih[1 * H + l];
    const float wi_g = W_ih[2 * H + l];
    const float wcx  = W_cg_x[l];
    const float bi   = b_ih[0 * H + l] + b_hh[0 * H + l];
    const float bf   = b_ih[1 * H + l] + b_hh[1 * H + l];
    const float bg   = b_ih[2 * H + l] + b_hh[2 * H + l];
    const float bc   = b_cg[l];

    // initial h = 0 (each 32-lane group owns its own slots)
    hs[sib * H + l] = (f16)0.0f;
    __syncthreads();

    float c = 0.0f;
    float h_out = 0.0f;
    const float* xrow = xs + sib * T;                  // uniform b32 per step
    const uint4* hp4 = (const uint4*)(hs + sib * H);   // 4 x 16B, uniform addr
    f16* hw = hs + sib * H + l;

    #pragma unroll 1
    for (int t = 0; t < T; ++t) {
        const float xt = xrow[t];

        float aI = fmaf(xt, wi_i, bi);
        float aF = fmaf(xt, wi_f, bf);
        float aG = fmaf(xt, wi_g, bg);
        float aC = fmaf(xt, wcx,  bc);

        // h-quads read just-in-time: only one uint4 live at a time
        #pragma unroll
        for (int q = 0; q < 4; ++q) {
            const uint4 hr = hp4[q];
            DOTBLK(hr.x, 4*q+0)
            DOTBLK(hr.y, 4*q+1)
            DOTBLK(hr.z, 4*q+2)
            DOTBLK(hr.w, 4*q+3)
        }

        const float ig = sigmoid_f(aI);
        const float fg = sigmoid_f(aF);
        const float gg = tanh_f(aG);
        const float cg = sigmoid_f(aC);   // contextual gate (prev h)
        c = fmaf(fg, c, ig * gg);
        h_out = cg * tanh_f(c);           // o-gate dead in reference

        *hw = (f16)h_out;   // publish for next step (same-wave consumers)
    }

    out[(size_t)seq * H + l] = h_out;
}

extern "C" void kernel_launch(void* const* d_in, const int* in_sizes, int n_in,
                              void* d_out, int out_size, void* d_ws, size_t ws_size,
                              hipStream_t stream) {
    const float* x      = (const float*)d_in[0];
    const float* W_ih   = (const float*)d_in[1];
    const float* W_hh   = (const float*)d_in[2];
    const float* b_ih   = (const float*)d_in[3];
    const float* b_hh   = (const float*)d_in[4];
    const float* W_cg_x = (const float*)d_in[5];
    const float* W_cg_h = (const float*)d_in[6];
    const float* b_cg   = (const float*)d_in[7];
    float* out = (float*)d_out;

    const int grid = NSEQ / SEQ_PER_BLOCK;   // 2304
    cglstm_kernel<<<grid, BLOCK, 0, stream>>>(
        x, W_ih, W_hh, b_ih, b_hh, W_cg_x, W_cg_h, b_cg, out);
}

// Round 9
// 237.316 us; speedup vs baseline: 1.1887x; 1.1887x over previous
//
#include <hip/hip_runtime.h>

// DACGLSTMExpert: 18432 independent CGLSTM sequences, T=120, H=32, DIN=1.
//
// MFMA reformulation (round 9). Rounds 1-8 showed the dot2/VALU design is
// stuck at ~230 VALU instr/step because the register allocator insists on
// AGPR-parking any large per-lane weight array (VGPR_Count pinned 64-88;
// ~130 v_accvgpr_read per step). Here the recurrent matvec runs on the
// MFMA pipe instead: one wave owns 16 sequences; per timestep
//   Gates[16 seqs x 128 gc] = h[16x32] @ W^T[32x128] + C_in
// as 8 x mfma_f32_16x16x32_f16 (tiles: i,i,f,f,g,g,cg,cg — o-gate is dead
// code in the reference, validated rounds 1-8). Weights become 32 shared
// B-frag VGPRs (vs 64/lane replicated), and MFMA reads AGPRs natively, so
// the allocator war dissolves. C_in = x[s]*w_in[gc]+b[gc] is the MFMA
// C-operand (f32, exact).
//
// Fragment conventions (16x16x32): C/D verified (learn_hip m89):
//   col = lane&15, row = 4*(lane>>4) + reg.
// A/B k-mapping: hardware pairs A elem j of lane-group g with B elem j of
// lane-group g; any k<->(g,j) bijection works if A and B use the SAME one.
// We use k = 8*(lane>>4) + j for both. A: lane&15 = seq row. B: lane&15 =
// gate col.
//
// Per-step h relayout (D-frag f32 -> A-frag f16) goes through a 1KB LDS
// buffer with slot swizzle sigma(l) = (l & ~3) | ((l ^ (l>>3)) & 3)
// (bits: s2=l2, s1=l1^l4, s0=l0^l3). This makes BOTH the per-lane
// ds_read_b128 (slots consecutive-mod-8 within each 8-lane phase) and the
// 8 ds_write_b16 (8 active slots distinct mod 8, 2 lanes/dword) <=2-way,
// i.e. conflict-free. Single-wave blocks make the write(t)->read(t+1)
// ordering race-free by construction.

constexpr int T = 120;
constexpr int H = 32;
constexpr int NSEQ = 2048 * 9;         // 18432
constexpr int SEQ_PER_BLOCK = 16;      // one wave, one MFMA M-dim
constexpr int BLOCK = 64;

typedef _Float16 f16;
typedef _Float16 f16x8 __attribute__((ext_vector_type(8)));
typedef float f32x4 __attribute__((ext_vector_type(4)));

#define LOG2E 1.4426950408889634f

__device__ __forceinline__ float fast_rcp(float x) {
    return __builtin_amdgcn_rcpf(x);
}
__device__ __forceinline__ float fast_exp2(float x) {
    return __builtin_amdgcn_exp2f(x);
}
// sigmoid(x) = 1 / (1 + 2^(-x*log2e))
__device__ __forceinline__ float sigmoid_f(float x) {
    return fast_rcp(1.0f + fast_exp2(-LOG2E * x));
}
// tanh(x) = 1 - 2/(2^(2x*log2e) + 1)
__device__ __forceinline__ float tanh_f(float x) {
    return fmaf(-2.0f, fast_rcp(1.0f + fast_exp2(2.0f * LOG2E * x)), 1.0f);
}

__global__ __launch_bounds__(BLOCK, 1)   // min 1 wave/EU -> full VGPR budget
void cglstm_mfma_kernel(
    const float* __restrict__ x,      // [NSEQ, T]
    const float* __restrict__ W_ih,   // [4H, 1]
    const float* __restrict__ W_hh,   // [4H, H]
    const float* __restrict__ b_ih,   // [4H]
    const float* __restrict__ b_hh,   // [4H]
    const float* __restrict__ W_cg_x, // [H, 1]
    const float* __restrict__ W_cg_h, // [H, H]
    const float* __restrict__ b_cg,   // [H]
    float* __restrict__ out)          // [NSEQ, H]
{
    __shared__ float xsT[T * 16];                    // x transposed: [t][seq]
    __shared__ __align__(16) f16 hbuf[64 * 8];       // A-frag slots, 1 KiB

    const int l   = threadIdx.x;       // 0..63
    const int m15 = l & 15;
    const int g   = l >> 4;
    const int sb  = blockIdx.x * SEQ_PER_BLOCK;

    // --- stage x transposed: x[(sb+s)*T + t] = x[sb*T + i] with i = s*T+t,
    //     so global reads are perfectly linear/coalesced ---
    {
        const float* xb = x + (size_t)sb * T;
        for (int i = l; i < SEQ_PER_BLOCK * T; i += BLOCK) {
            int s = i / T;
            int t = i - s * T;
            xsT[t * 16 + s] = xb[i];
        }
    }

    // --- B fragments: 8 gate tiles, f16, k = 8g + j, col n = m15 ---
    f16x8 bt[8];
    #pragma unroll
    for (int tile = 0; tile < 8; ++tile) {
        const float* wrow = (tile < 6)
            ? (W_hh   + (size_t)(tile * 16 + m15) * H + 8 * g)         // i,f,g rows 0..95
            : (W_cg_h + (size_t)((tile - 6) * 16 + m15) * H + 8 * g);  // cg rows
        f32x4 wa = *(const f32x4*)(wrow);
        f32x4 wb = *(const f32x4*)(wrow + 4);
        bt[tile] = f16x8{(f16)wa.x, (f16)wa.y, (f16)wa.z, (f16)wa.w,
                         (f16)wb.x, (f16)wb.y, (f16)wb.z, (f16)wb.w};
    }

    // --- per-tile input weight / bias scalars (gate col n = tile*16+m15) ---
    float w_in[8], bias[8];
    #pragma unroll
    for (int tile = 0; tile < 8; ++tile) {
        const int n = tile * 16 + m15;
        if (tile < 6) { w_in[tile] = W_ih[n];        bias[tile] = b_ih[n] + b_hh[n]; }
        else          { w_in[tile] = W_cg_x[n - 96]; bias[tile] = b_cg[n - 96]; }
    }

    // --- LDS slot addressing (see header comment for the swizzle) ---
    const int slot_r = (l & ~3) | ((l ^ (l >> 3)) & 3);   // this lane's A-frag slot
    int waddr[2][4];
    #pragma unroll
    for (int p = 0; p < 2; ++p) {
        #pragma unroll
        for (int r = 0; r < 4; ++r) {
            // value h[s = 4g+r][k = 16p + m15] -> slot lane lp = (k>>3)*16 + s
            const int lp = ((2 * p + (m15 >> 3)) << 4) | (4 * g + r);
            const int sp = (lp & ~3) | ((lp ^ (lp >> 3)) & 3);
            waddr[p][r] = sp * 16 + (m15 & 7) * 2;        // byte address
        }
    }

    // --- h(0) = 0 ---
    *(f16x8*)(hbuf + slot_r * 8) = f16x8{0, 0, 0, 0, 0, 0, 0, 0};
    __syncthreads();

    float c_st[2][4] = {};
    char* hbase = (char*)hbuf;

    #pragma unroll 1
    for (int t = 0; t < T; ++t) {
        // x for this wave's 4 seq-rows (broadcast reads within 16-lane group)
        const f32x4 xq = *(const f32x4*)(xsT + t * 16 + 4 * g);
        // A fragment: h[m15][8g .. 8g+7] as f16
        const f16x8 af = *(const f16x8*)(hbuf + slot_r * 8);

        f32x4 d[8];
        #pragma unroll
        for (int tile = 0; tile < 8; ++tile) {
            f32x4 cin;
            cin.x = fmaf(xq.x, w_in[tile], bias[tile]);
            cin.y = fmaf(xq.y, w_in[tile], bias[tile]);
            cin.z = fmaf(xq.z, w_in[tile], bias[tile]);
            cin.w = fmaf(xq.w, w_in[tile], bias[tile]);
            d[tile] = __builtin_amdgcn_mfma_f32_16x16x32_f16(af, bt[tile], cin, 0, 0, 0);
        }

        // elementwise gates; lane holds (s = 4g+r, hcol = 16p + m15)
        #pragma unroll
        for (int p = 0; p < 2; ++p) {
            #pragma unroll
            for (int r = 0; r < 4; ++r) {
                const float ig = sigmoid_f(d[0 + p][r]);
                const float fg = sigmoid_f(d[2 + p][r]);
                const float gg = tanh_f(d[4 + p][r]);
                const float cg = sigmoid_f(d[6 + p][r]);   // contextual gate (prev h)
                const float cv = fmaf(fg, c_st[p][r], ig * gg);
                c_st[p][r] = cv;
                const f16 hf = (f16)(cg * tanh_f(cv));      // o-gate dead
                *(f16*)(hbase + waddr[p][r]) = hf;          // publish for t+1
            }
        }
    }

    // --- epilogue: final h sits in hbuf in A-frag layout; store coalesced-ish ---
    const f16x8 hfin = *(const f16x8*)(hbuf + slot_r * 8);
    float* orow = out + (size_t)(sb + m15) * H + 8 * g;
    #pragma unroll
    for (int j = 0; j < 8; ++j) orow[j] = (float)hfin[j];
}

extern "C" void kernel_launch(void* const* d_in, const int* in_sizes, int n_in,
                              void* d_out, int out_size, void* d_ws, size_t ws_size,
                              hipStream_t stream) {
    const float* x      = (const float*)d_in[0];
    const float* W_ih   = (const float*)d_in[1];
    const float* W_hh   = (const float*)d_in[2];
    const float* b_ih   = (const float*)d_in[3];
    const float* b_hh   = (const float*)d_in[4];
    const float* W_cg_x = (const float*)d_in[5];
    const float* W_cg_h = (const float*)d_in[6];
    const float* b_cg   = (const float*)d_in[7];
    float* out = (float*)d_out;

    const int grid = NSEQ / SEQ_PER_BLOCK;   // 1152 one-wave blocks
    cglstm_mfma_kernel<<<grid, BLOCK, 0, stream>>>(
        x, W_ih, W_hh, b_ih, b_hh, W_cg_x, W_cg_h, b_cg, out);
}

// Round 10
// 207.791 us; speedup vs baseline: 1.3576x; 1.1421x over previous
//
#include <hip/hip_runtime.h>

// DACGLSTMExpert: 18432 independent CGLSTM sequences, T=120, H=32, DIN=1.
//
// Round-10: MFMA formulation (validated round 9: correct A/B k-pairing and
// C/D layout, absmax 9.8e-4) restructured as 2 waves per 16-seq block.
// Round-9 miss analysis: 3640 cyc/step = naked latency (1.1 wave/SIMD) +
// trans-pipe saturation (80 quarter-rate exp/rcp per wave-step).
// Wave w owns gate-column half w: 4 MFMAs (i,f,g,cg x 16 cols) + the
// elementwise for (all 16 seqs) x (its 16 hcols) -> 4 positions/lane,
// 40 trans/step (was 80), and 2304 waves total (was 1152).
//
// Per timestep: Gates[16 seq x 64 gc_half] = h[16x32] @ W_half^T + C_in,
// C_in = x[s]*w_in[gc] + b[gc] as the MFMA C operand (f32, exact).
// o-gate is dead code in the reference and skipped (validated rounds 1-9).
//
// Fragment conventions (16x16x32 f16), verified round 9 end-to-end:
//   C/D: lane(g,m15) reg r holds D[seq=4g+r][col=m15]  (learn_hip m89)
//   A/B: k = 8*(lane>>4) + j for both operands (same bijection -> valid).
//
// h relayout D->A goes through a double-buffered LDS buffer of 64 16B
// slots, slot id L = (k>>3)*16 + s, placed at sigma(L) with
// sigma(L) = (L & ~3) | ((L ^ (L>>3)) & 3)  (round-9 validated; measured
// conflict cost ~7 cyc/step). One __syncthreads per step publishes h(t+1):
// reads of buf[cur] complete before the barrier (lgkmcnt drain), so the
// next step's writes into buf[cur] are WAR-safe.

constexpr int T = 120;
constexpr int H = 32;
constexpr int NSEQ = 2048 * 9;         // 18432
constexpr int SEQ_PER_BLOCK = 16;
constexpr int BLOCK = 128;             // 2 waves; wave w = gate-col half w

typedef _Float16 f16;
typedef _Float16 f16x8 __attribute__((ext_vector_type(8)));
typedef float f32x4 __attribute__((ext_vector_type(4)));

#define LOG2E 1.4426950408889634f

__device__ __forceinline__ float fast_rcp(float x) {
    return __builtin_amdgcn_rcpf(x);
}
__device__ __forceinline__ float fast_exp2(float x) {
    return __builtin_amdgcn_exp2f(x);
}
// sigmoid(x) = 1 / (1 + 2^(-x*log2e))
__device__ __forceinline__ float sigmoid_f(float x) {
    return fast_rcp(1.0f + fast_exp2(-LOG2E * x));
}
// tanh(x) = 1 - 2/(2^(2x*log2e) + 1)
__device__ __forceinline__ float tanh_f(float x) {
    return fmaf(-2.0f, fast_rcp(1.0f + fast_exp2(2.0f * LOG2E * x)), 1.0f);
}

__device__ __forceinline__ int slot_swz(int L) {
    return (L & ~3) | ((L ^ (L >> 3)) & 3);
}

__global__ __launch_bounds__(BLOCK, 1)
void cglstm_kernel(
    const float* __restrict__ x,      // [NSEQ, T]
    const float* __restrict__ W_ih,   // [4H, 1]
    const float* __restrict__ W_hh,   // [4H, H]
    const float* __restrict__ b_ih,   // [4H]
    const float* __restrict__ b_hh,   // [4H]
    const float* __restrict__ W_cg_x, // [H, 1]
    const float* __restrict__ W_cg_h, // [H, H]
    const float* __restrict__ b_cg,   // [H]
    float* __restrict__ out)          // [NSEQ, H]
{
    __shared__ float xsT[T * 16];                     // x transposed [t][seq]
    __shared__ __align__(16) f16 hbuf[2][64 * 8];     // double-buffered slots

    const int tid = threadIdx.x;
    const int wv  = tid >> 6;          // wave = gate-col half (0/1)
    const int l   = tid & 63;
    const int m15 = l & 15;
    const int g   = l >> 4;            // 0..3
    const int sb  = blockIdx.x * SEQ_PER_BLOCK;

    // --- stage x transposed (global reads perfectly linear) ---
    {
        const float* xb = x + (size_t)sb * T;
        for (int i = tid; i < SEQ_PER_BLOCK * T; i += BLOCK) {
            int s = i / T;
            int t = i - s * T;
            xsT[t * 16 + s] = xb[i];
        }
    }
    // --- zero h(0) buffer ---
    if (tid < 64) ((uint4*)&hbuf[0][0])[tid] = uint4{0, 0, 0, 0};

    // --- B fragments + input-weight/bias scalars for this wave's half ---
    const int ncol = wv * 16 + m15;    // column within each 32-wide gate
    f16x8 bt[4];
    float w_in[4], bias[4];
    #pragma unroll
    for (int gate = 0; gate < 4; ++gate) {
        const float* wrow = (gate < 3)
            ? (W_hh   + (size_t)(gate * 32 + ncol) * H + 8 * g)  // i,f,g
            : (W_cg_h + (size_t)ncol * H + 8 * g);               // cg
        f32x4 wa = *(const f32x4*)wrow;
        f32x4 wb = *(const f32x4*)(wrow + 4);
        bt[gate] = f16x8{(f16)wa.x, (f16)wa.y, (f16)wa.z, (f16)wa.w,
                         (f16)wb.x, (f16)wb.y, (f16)wb.z, (f16)wb.w};
        if (gate < 3) {
            w_in[gate] = W_ih[gate * 32 + ncol];
            bias[gate] = b_ih[gate * 32 + ncol] + b_hh[gate * 32 + ncol];
        } else {
            w_in[gate] = W_cg_x[ncol];
            bias[gate] = b_cg[ncol];
        }
    }

    // --- LDS addresses ---
    const int rdoff = slot_swz(g * 16 + m15) * 16;    // A-frag: s=m15, kq=g
    int wroff[4];
    #pragma unroll
    for (int r = 0; r < 4; ++r) {
        const int kq = 2 * wv + (m15 >> 3);           // k = 16*wv + m15
        const int Lw = kq * 16 + 4 * g + r;           // s = 4g + r
        wroff[r] = slot_swz(Lw) * 16 + (m15 & 7) * 2;
    }

    __syncthreads();

    float c_st[4] = {0.0f, 0.0f, 0.0f, 0.0f};
    float h_keep[4] = {0.0f, 0.0f, 0.0f, 0.0f};
    int cur = 0;

    #pragma unroll 1
    for (int t = 0; t < T; ++t) {
        // x for this lane's 4 seq rows (uniform within 16-lane group)
        const f32x4 xq = *(const f32x4*)(xsT + t * 16 + 4 * g);
        // A fragment: h[m15][8g..8g+7] as f16
        const f16x8 af = *(const f16x8*)((const char*)&hbuf[cur][0] + rdoff);

        f32x4 d[4];
        #pragma unroll
        for (int gate = 0; gate < 4; ++gate) {
            f32x4 acc;
            acc.x = fmaf(xq.x, w_in[gate], bias[gate]);
            acc.y = fmaf(xq.y, w_in[gate], bias[gate]);
            acc.z = fmaf(xq.z, w_in[gate], bias[gate]);
            acc.w = fmaf(xq.w, w_in[gate], bias[gate]);
            d[gate] = __builtin_amdgcn_mfma_f32_16x16x32_f16(af, bt[gate], acc, 0, 0, 0);
        }

        // elementwise gates for (seq = 4g+r, hcol = ncol)
        char* wbase = (char*)&hbuf[cur ^ 1][0];
        #pragma unroll
        for (int r = 0; r < 4; ++r) {
            const float ig = sigmoid_f(d[0][r]);
            const float fg = sigmoid_f(d[1][r]);
            const float gg = tanh_f(d[2][r]);
            const float cg = sigmoid_f(d[3][r]);   // contextual gate (prev h)
            const float cv = fmaf(fg, c_st[r], ig * gg);
            c_st[r] = cv;
            const float hv = cg * tanh_f(cv);      // o-gate dead in reference
            h_keep[r] = hv;
            *(f16*)(wbase + wroff[r]) = (f16)hv;   // publish h(t+1)
        }

        __syncthreads();
        cur ^= 1;
    }

    // --- epilogue: final h straight from registers (f32, coalesced) ---
    #pragma unroll
    for (int r = 0; r < 4; ++r)
        out[(size_t)(sb + 4 * g + r) * H + ncol] = h_keep[r];
}

extern "C" void kernel_launch(void* const* d_in, const int* in_sizes, int n_in,
                              void* d_out, int out_size, void* d_ws, size_t ws_size,
                              hipStream_t stream) {
    const float* x      = (const float*)d_in[0];
    const float* W_ih   = (const float*)d_in[1];
    const float* W_hh   = (const float*)d_in[2];
    const float* b_ih   = (const float*)d_in[3];
    const float* b_hh   = (const float*)d_in[4];
    const float* W_cg_x = (const float*)d_in[5];
    const float* W_cg_h = (const float*)d_in[6];
    const float* b_cg   = (const float*)d_in[7];
    float* out = (float*)d_out;

    const int grid = NSEQ / SEQ_PER_BLOCK;   // 1152 blocks x 2 waves = 2304 waves
    cglstm_kernel<<<grid, BLOCK, 0, stream>>>(
        x, W_ih, W_hh, b_ih, b_hh, W_cg_x, W_cg_h, b_cg, out);
}

// Round 12
// 206.720 us; speedup vs baseline: 1.3646x; 1.0052x over previous
//
#include <hip/hip_runtime.h>

// DACGLSTMExpert: 18432 independent CGLSTM sequences, T=120, H=32, DIN=1.
//
// Round-11: round-10 validated structure (2 waves/block, 16 seqs, gate-col
// halves, slot-swizzled double-buffered LDS h exchange) + exp-space FUSED
// activations. Round-10 counters pinned v_exp/v_rcp at ~16 cyc/wave64
// (1/8 rate): trans issue dominates. Fusion (exact algebra, not approx):
//   c' = f*c + i*g = [c*pa*pg + (eg-1)*pf] / (pa*pg*pf)   ... 1 rcp (was 3)
//   h  = cg*tanh(c') = (ec-1) / [(1+ecg)(1+ec)]           ... 1 rcp (was 2)
// with ea=e^-aI, ef=e^-aF, eg=e^2aG, ecg=e^-aC, ec=e^2c' -> 7 trans/position
// (was 10). Only the ec arg needs an overflow clamp (c drifts over T=120;
// exp2 arg capped at 38 so all fused denominators stay < 1e24 << f32 max).
// o-gate is dead code in the reference and skipped (validated rounds 1-10).
//
// Fragment conventions (16x16x32 f16), verified end-to-end rounds 9-10:
//   C/D: lane(g,m15) reg r holds D[seq=4g+r][col=m15]
//   A/B: k = 8*(lane>>4) + j for both operands (same bijection -> valid).

constexpr int T = 120;
constexpr int H = 32;
constexpr int NSEQ = 2048 * 9;         // 18432
constexpr int SEQ_PER_BLOCK = 16;
constexpr int BLOCK = 128;             // 2 waves; wave w = gate-col half w

typedef _Float16 f16;
typedef _Float16 f16x8 __attribute__((ext_vector_type(8)));
typedef float f32x4 __attribute__((ext_vector_type(4)));

#define LOG2E 1.4426950408889634f

__device__ __forceinline__ float fast_rcp(float x) {
    return __builtin_amdgcn_rcpf(x);
}
__device__ __forceinline__ float fast_exp2(float x) {
    return __builtin_amdgcn_exp2f(x);
}

__device__ __forceinline__ int slot_swz(int L) {
    return (L & ~3) | ((L ^ (L >> 3)) & 3);
}

__global__ __launch_bounds__(BLOCK, 1)
void cglstm_kernel(
    const float* __restrict__ x,      // [NSEQ, T]
    const float* __restrict__ W_ih,   // [4H, 1]
    const float* __restrict__ W_hh,   // [4H, H]
    const float* __restrict__ b_ih,   // [4H]
    const float* __restrict__ b_hh,   // [4H]
    const float* __restrict__ W_cg_x, // [H, 1]
    const float* __restrict__ W_cg_h, // [H, H]
    const float* __restrict__ b_cg,   // [H]
    float* __restrict__ out)          // [NSEQ, H]
{
    __shared__ float xsT[T * 16];                     // x transposed [t][seq]
    __shared__ __align__(16) f16 hbuf[2][64 * 8];     // double-buffered slots

    const int tid = threadIdx.x;
    const int wv  = tid >> 6;          // wave = gate-col half (0/1)
    const int l   = tid & 63;
    const int m15 = l & 15;
    const int g   = l >> 4;            // 0..3
    const int sb  = blockIdx.x * SEQ_PER_BLOCK;

    // --- stage x transposed (global reads perfectly linear) ---
    {
        const float* xb = x + (size_t)sb * T;
        for (int i = tid; i < SEQ_PER_BLOCK * T; i += BLOCK) {
            int s = i / T;
            int t = i - s * T;
            xsT[t * 16 + s] = xb[i];
        }
    }
    // --- zero h(0) buffer ---
    if (tid < 64) ((uint4*)&hbuf[0][0])[tid] = uint4{0, 0, 0, 0};

    // --- B fragments + input-weight/bias scalars for this wave's half ---
    const int ncol = wv * 16 + m15;    // column within each 32-wide gate
    f16x8 bt[4];
    float w_in[4], bias[4];
    #pragma unroll
    for (int gate = 0; gate < 4; ++gate) {
        const float* wrow = (gate < 3)
            ? (W_hh   + (size_t)(gate * 32 + ncol) * H + 8 * g)  // i,f,g
            : (W_cg_h + (size_t)ncol * H + 8 * g);               // cg
        f32x4 wa = *(const f32x4*)wrow;
        f32x4 wb = *(const f32x4*)(wrow + 4);
        bt[gate] = f16x8{(f16)wa.x, (f16)wa.y, (f16)wa.z, (f16)wa.w,
                         (f16)wb.x, (f16)wb.y, (f16)wb.z, (f16)wb.w};
        if (gate < 3) {
            w_in[gate] = W_ih[gate * 32 + ncol];
            bias[gate] = b_ih[gate * 32 + ncol] + b_hh[gate * 32 + ncol];
        } else {
            w_in[gate] = W_cg_x[ncol];
            bias[gate] = b_cg[ncol];
        }
    }

    // --- LDS addresses ---
    const int rdoff = slot_swz(g * 16 + m15) * 16;    // A-frag: s=m15, kq=g
    int wroff[4];
    #pragma unroll
    for (int r = 0; r < 4; ++r) {
        const int kq = 2 * wv + (m15 >> 3);           // k = 16*wv + m15
        const int Lw = kq * 16 + 4 * g + r;           // s = 4g + r
        wroff[r] = slot_swz(Lw) * 16 + (m15 & 7) * 2;
    }

    __syncthreads();

    float c_st[4] = {0.0f, 0.0f, 0.0f, 0.0f};
    float h_keep[4] = {0.0f, 0.0f, 0.0f, 0.0f};
    int cur = 0;

    #pragma unroll 1
    for (int t = 0; t < T; ++t) {
        // x for this lane's 4 seq rows (uniform within 16-lane group)
        const f32x4 xq = *(const f32x4*)(xsT + t * 16 + 4 * g);
        // A fragment: h[m15][8g..8g+7] as f16
        const f16x8 af = *(const f16x8*)((const char*)&hbuf[cur][0] + rdoff);

        f32x4 d[4];
        #pragma unroll
        for (int gate = 0; gate < 4; ++gate) {
            f32x4 acc = xq * w_in[gate] + bias[gate];   // v_pk_fma_f32 x2
            d[gate] = __builtin_amdgcn_mfma_f32_16x16x32_f16(af, bt[gate], acc, 0, 0, 0);
        }

        // fused exp-space elementwise for (seq = 4g+r, hcol = ncol)
        char* wbase = (char*)&hbuf[cur ^ 1][0];
        #pragma unroll
        for (int r = 0; r < 4; ++r) {
            const float ea  = fast_exp2(-LOG2E * d[0][r]);          // e^-aI
            const float ef  = fast_exp2(-LOG2E * d[1][r]);          // e^-aF
            const float eg  = fast_exp2(2.0f * LOG2E * d[2][r]);    // e^2aG
            const float ecg = fast_exp2(-LOG2E * d[3][r]);          // e^-aC
            const float pa = 1.0f + ea, pf = 1.0f + ef, pg = 1.0f + eg;
            const float den  = pa * pg;
            const float num  = fmaf(c_st[r], den, (eg - 1.0f) * pf);
            const float cv   = num * fast_rcp(den * pf);
            c_st[r] = cv;
            // h = cg * tanh(cv); clamp exp arg (cv can drift over T steps)
            const float ec   = fast_exp2(fminf(2.0f * LOG2E * cv, 38.0f));
            const float hv   = (ec - 1.0f) * fast_rcp((1.0f + ecg) * (1.0f + ec));
            h_keep[r] = hv;
            *(f16*)(wbase + wroff[r]) = (f16)hv;        // publish h(t+1)
        }

        __syncthreads();
        cur ^= 1;
    }

    // --- epilogue: final h straight from registers (f32, coalesced) ---
    #pragma unroll
    for (int r = 0; r < 4; ++r)
        out[(size_t)(sb + 4 * g + r) * H + ncol] = h_keep[r];
}

extern "C" void kernel_launch(void* const* d_in, const int* in_sizes, int n_in,
                              void* d_out, int out_size, void* d_ws, size_t ws_size,
                              hipStream_t stream) {
    const float* x      = (const float*)d_in[0];
    const float* W_ih   = (const float*)d_in[1];
    const float* W_hh   = (const float*)d_in[2];
    const float* b_ih   = (const float*)d_in[3];
    const float* b_hh   = (const float*)d_in[4];
    const float* W_cg_x = (const float*)d_in[5];
    const float* W_cg_h = (const float*)d_in[6];
    const float* b_cg   = (const float*)d_in[7];
    float* out = (float*)d_out;

    const int grid = NSEQ / SEQ_PER_BLOCK;   // 1152 blocks x 2 waves
    cglstm_kernel<<<grid, BLOCK, 0, stream>>>(
        x, W_ih, W_hh, b_ih, b_hh, W_cg_x, W_cg_h, b_cg, out);
}